// Round 16
// baseline (165.991 us; speedup 1.0000x reference)
//
#include <hip/hip_runtime.h>
#include <hip/hip_bf16.h>

#define NROWS 8192
#define NDIM  256
#define KNN   8
#define TCOL  32                          // j-cols per LDS tile (16 KiB)
#define BLK_ROWS 128                      // 4 waves x 32 rows (R=1)
#define JSPLIT 16
#define JRANGE (NROWS / JSPLIT)           // 512
#define NBX    (NROWS / BLK_ROWS)         // 64 row-blocks

typedef __attribute__((ext_vector_type(8)))  short bf16x8;
typedef __attribute__((ext_vector_type(16))) float f32x16;

// ---- workspace layout (bytes) ----
// ebT chunk-major: ushort ebT[32][NROWS][8] — chunk c holds dims 8c..8c+7.
#define WS_EBT 0                          // 4 MiB
#define WS_SQN (4*1024*1024)              // 32 KiB
#define WS_COL (WS_SQN + 32*1024)         // colsum[256] (atomics)
#define WS_ACC (WS_COL + 1024)            // gacc[0]=sum8 [1]=S2 [2]=Q-unused [3]=pad
#define WS_CNT (WS_ACC + 64)              // cnt[64] + gcnt (ints)
#define WS_KNN (WS_ACC + 1024)            // [16][NROWS][KNN] f32 = 4 MiB

// e -> bf16 chunk-major, per-row squared norms, colsum atomics, S2 atomics.
__global__ void k_prep(const float* __restrict__ e,
                       ushort* __restrict__ ebt,
                       float* __restrict__ sqn,
                       float* __restrict__ colsum,
                       float* __restrict__ gacc) {
  __shared__ float lcs[NDIM];
  const int tid  = threadIdx.x;
  const int lane = tid & 63;
  const int wv   = tid >> 6;
  lcs[tid] = 0.f;
  __syncthreads();
  const int chunk = lane >> 1;
  const int half  = lane & 1;
  float4 cs = {0.f, 0.f, 0.f, 0.f};
  float s2loc = 0.f;
  #pragma unroll
  for (int r = 0; r < 8; ++r) {
    const int row = blockIdx.x * 32 + wv * 8 + r;
    const float4 v = *reinterpret_cast<const float4*>(e + (size_t)row * NDIM + lane * 4);
    ushort4 o;
    __hip_bfloat16 b0 = __float2bfloat16(v.x), b1 = __float2bfloat16(v.y);
    __hip_bfloat16 b2 = __float2bfloat16(v.z), b3 = __float2bfloat16(v.w);
    o.x = *reinterpret_cast<ushort*>(&b0); o.y = *reinterpret_cast<ushort*>(&b1);
    o.z = *reinterpret_cast<ushort*>(&b2); o.w = *reinterpret_cast<ushort*>(&b3);
    *reinterpret_cast<ushort4*>(ebt + ((size_t)(chunk * NROWS + row) * 8 + half * 4)) = o;
    float acc = v.x*v.x + v.y*v.y + v.z*v.z + v.w*v.w;
    #pragma unroll
    for (int off = 32; off > 0; off >>= 1) acc += __shfl_down(acc, off);
    if (lane == 0) { sqn[row] = acc; s2loc += acc; }
    cs.x += v.x; cs.y += v.y; cs.z += v.z; cs.w += v.w;
  }
  atomicAdd(&lcs[lane * 4 + 0], cs.x);
  atomicAdd(&lcs[lane * 4 + 1], cs.y);
  atomicAdd(&lcs[lane * 4 + 2], cs.z);
  atomicAdd(&lcs[lane * 4 + 3], cs.w);
  if (lane == 0) atomicAdd(&gacc[1], s2loc);     // S2 partial (memset'd first)
  __syncthreads();
  atomicAdd(&colsum[tid], lcs[tid]);
}

// ---- selection helpers (MAX-key; key = dot - nj/2, larger = nearer) ----
__device__ __forceinline__ void CEmax(float& x, float& y) {
  const float h = fmaxf(x, y);
  y = fminf(x, y);
  x = h;
}
__device__ __forceinline__ void clean8max(float* s) {   // bitonic -> descending
  CEmax(s[0],s[4]); CEmax(s[1],s[5]); CEmax(s[2],s[6]); CEmax(s[3],s[7]);
  CEmax(s[0],s[2]); CEmax(s[1],s[3]); CEmax(s[4],s[6]); CEmax(s[5],s[7]);
  CEmax(s[0],s[1]); CEmax(s[2],s[3]); CEmax(s[4],s[5]); CEmax(s[6],s[7]);
}
__device__ __forceinline__ void ins8max(float* m, const float c) {  // desc insert
  m[7] = __builtin_amdgcn_fmed3f(m[6], m[7], c);
  m[6] = __builtin_amdgcn_fmed3f(m[5], m[6], c);
  m[5] = __builtin_amdgcn_fmed3f(m[4], m[5], c);
  m[4] = __builtin_amdgcn_fmed3f(m[3], m[4], c);
  m[3] = __builtin_amdgcn_fmed3f(m[2], m[3], c);
  m[2] = __builtin_amdgcn_fmed3f(m[1], m[2], c);
  m[1] = __builtin_amdgcn_fmed3f(m[0], m[1], c);
  m[0] = fmaxf(m[0], c);
}
__device__ __forceinline__ void CEmin(float& x, float& y) {
  const float lo = fminf(x, y);
  y = fmaxf(x, y);
  x = lo;
}
__device__ __forceinline__ void clean8min(float* s) {   // bitonic -> ascending
  CEmin(s[0],s[4]); CEmin(s[1],s[5]); CEmin(s[2],s[6]); CEmin(s[3],s[7]);
  CEmin(s[0],s[2]); CEmin(s[1],s[3]); CEmin(s[4],s[6]); CEmin(s[5],s[7]);
  CEmin(s[0],s[1]); CEmin(s[2],s[3]); CEmin(s[4],s[5]); CEmin(s[6],s[7]);
}

// r13 core (R=1, 4 blocks/CU, chunk-major ebT, counted-vmcnt pipeline)
// + T5 setprio around MFMA + fused finalization tail:
//   last split-block per bx merges its 128 rows (16 sorted lists each),
//   atomicAdds sum8; globally-last merger computes Q and the scalar.
__launch_bounds__(256, 4)
__global__ void k_main(const ushort* __restrict__ ebt,
                       const float* __restrict__ sqn,
                       float* __restrict__ knn_out,
                       const float* __restrict__ colsum,
                       float* __restrict__ gacc,
                       int* __restrict__ cnt,
                       float* __restrict__ out) {
  __shared__ ushort lbuf[2][TCOL * NDIM];   // 2 x 16 KiB
  char* const lraw = reinterpret_cast<char*>(&lbuf[0][0]);
  __shared__ int flag;
  __shared__ float red[8];

  const int tid  = threadIdx.x;
  const int lane = tid & 63;
  const int wv   = tid >> 6;
  const int col  = lane & 31;
  const int hi   = lane >> 5;
  const int bx   = blockIdx.x;
  const int rowi = bx * BLK_ROWS + wv * 32 + col;
  const int split = blockIdx.y;
  const int jbase = split * JRANGE;

  bf16x8 ifr[16];
  #pragma unroll
  for (int kk = 0; kk < 16; ++kk)
    ifr[kk] = *reinterpret_cast<const bf16x8*>(
        ebt + (size_t)((2 * kk + hi) * NROWS + rowi) * 8);
  const float ni = sqn[rowi];

  float m[KNN];
  #pragma unroll
  for (int i = 0; i < KNN; ++i) m[i] = -1e30f;

  const ushort* sp[4];
  #pragma unroll
  for (int s = 0; s < 4; ++s) {
    const int c = s * 8 + (tid >> 5);
    sp[s] = ebt + (size_t)(c * NROWS + jbase + (tid & 31)) * 8;
  }
  const int lbase = hi * 512 + col * 16;

  auto STAGE = [&](int bufc) {
    #pragma unroll
    for (int s = 0; s < 4; ++s) {
      __builtin_amdgcn_global_load_lds(
          (const __attribute__((address_space(1))) void*)sp[s],
          (__attribute__((address_space(3))) void*)(
              lraw + bufc * 16384 + s * 4096 + wv * 1024),
          16, 0, 0);
      sp[s] += TCOL * 8;
    }
  };

  const float* njp = sqn + jbase;
  const int nT = JRANGE / TCOL;            // 16

  STAGE(0);
  STAGE(1);

  for (int t = 0; t < nT; ++t) {
    if (t + 1 < nT) {
      asm volatile("s_waitcnt vmcnt(4)" ::: "memory");
    } else {
      asm volatile("s_waitcnt vmcnt(0)" ::: "memory");
    }
    __builtin_amdgcn_s_barrier();
    asm volatile("" ::: "memory");

    {
      const int bufc = t & 1;
      f32x16 acc;
      #pragma unroll
      for (int g = 0; g < 4; ++g) {
        const float4 nj4 = *reinterpret_cast<const float4*>(njp + g * 8 + hi * 4);
        acc[g*4+0] = -0.5f * nj4.x; acc[g*4+1] = -0.5f * nj4.y;
        acc[g*4+2] = -0.5f * nj4.z; acc[g*4+3] = -0.5f * nj4.w;
      }
      __builtin_amdgcn_s_setprio(1);
      #pragma unroll
      for (int kk = 0; kk < 16; ++kk) {
        const bf16x8 jf = *reinterpret_cast<const bf16x8*>(
            lraw + bufc * 16384 + kk * 1024 + lbase);
        acc = __builtin_amdgcn_mfma_f32_32x32x16_bf16(jf, ifr[kk], acc, 0, 0, 0);
      }
      __builtin_amdgcn_s_setprio(0);
      #pragma unroll
      for (int q = 0; q < 16; ++q) ins8max(m, acc[q]);
      njp += TCOL;
    }

    asm volatile("" ::: "memory");
    __builtin_amdgcn_s_barrier();
    if (t + 2 < nT) STAGE(t & 1);
  }

  // per-row sorted ascending distances for this split
  float g[KNN];
  #pragma unroll
  for (int k = 0; k < KNN; ++k)
    g[k] = fmaxf(m[k], __shfl_xor(m[KNN - 1 - k], 32));
  clean8max(g);
  if (hi == 0) {
    float* dst = knn_out + ((size_t)split * NROWS + rowi) * KNN;
    #pragma unroll
    for (int k = 0; k < KNN; ++k)
      dst[k] = fmaxf(fmaf(-2.0f, g[k], ni), 0.0f);
  }

  // ---- completion tail: last split-block for bx merges its 128 rows ----
  __threadfence();
  __syncthreads();
  if (tid == 0) flag = (atomicAdd(&cnt[bx], 1) == JSPLIT - 1) ? 1 : 0;
  __syncthreads();
  if (!flag) return;

  float rs = 0.f;
  if (tid < BLK_ROWS) {
    const int row = bx * BLK_ROWS + tid;
    float mm[KNN];
    const float* p0 = knn_out + (size_t)row * KNN;
    #pragma unroll
    for (int i = 0; i < KNN; ++i) mm[i] = p0[i];
    for (int s = 1; s < JSPLIT; ++s) {
      const float* p = knn_out + ((size_t)s * NROWS + row) * KNN;
      float b[KNN];
      #pragma unroll
      for (int i = 0; i < KNN; ++i) b[i] = p[i];
      #pragma unroll
      for (int k = 0; k < KNN; ++k) mm[k] = fminf(mm[k], b[KNN - 1 - k]);
      clean8min(mm);
    }
    #pragma unroll
    for (int i = 0; i < KNN; ++i) rs += mm[i];
  }
  #pragma unroll
  for (int off = 32; off > 0; off >>= 1) rs += __shfl_down(rs, off);
  if (lane == 0) red[wv] = rs;
  __syncthreads();
  if (tid == 0) {
    atomicAdd(&gacc[0], red[0] + red[1] + red[2] + red[3]);
    __threadfence();
    flag = (atomicAdd(&cnt[NBX], 1) == NBX - 1) ? 1 : 0;
  }
  __syncthreads();
  if (!flag) return;

  // globally-last merger: Q from colsum, then the scalar.
  {
    const float cs = colsum[tid];
    float q = cs * cs;
    #pragma unroll
    for (int off = 32; off > 0; off >>= 1) q += __shfl_down(q, off);
    if (lane == 0) red[4 + wv] = q;
    __syncthreads();
    if (tid == 0) {
      const float Q    = red[4] + red[5] + red[6] + red[7];
      const float sum8 = atomicAdd(&gacc[0], 0.0f);
      const float S2   = atomicAdd(&gacc[1], 0.0f);
      const float ref_var = (S2 - Q / (float)NROWS) / ((float)NDIM * (float)(NROWS - 1));
      out[0] = (sum8 / (float)(NROWS * KNN)) / ref_var;
    }
  }
}

extern "C" void kernel_launch(void* const* d_in, const int* in_sizes, int n_in,
                              void* d_out, int out_size, void* d_ws, size_t ws_size,
                              hipStream_t stream) {
  const float* e = (const float*)d_in[0];
  char* ws = (char*)d_ws;
  ushort* ebt   = (ushort*)(ws + WS_EBT);
  float* sqn    = (float*)(ws + WS_SQN);
  float* colsum = (float*)(ws + WS_COL);
  float* gacc   = (float*)(ws + WS_ACC);
  int*   cnt    = (int*)(ws + WS_CNT);
  float* knn    = (float*)(ws + WS_KNN);
  float* out    = (float*)d_out;

  // zero colsum + gacc + counters (harness doesn't re-poison ws).
  hipMemsetAsync(ws + WS_COL, 0, 2048, stream);

  hipLaunchKernelGGL(k_prep, dim3(256), dim3(256), 0, stream, e, ebt, sqn, colsum, gacc);
  hipLaunchKernelGGL(k_main, dim3(NBX, JSPLIT), dim3(256), 0, stream,
                     ebt, sqn, knn, colsum, gacc, cnt, out);
}

// Round 17
// 71.876 us; speedup vs baseline: 2.3094x; 2.3094x over previous
//
#include <hip/hip_runtime.h>
#include <hip/hip_bf16.h>

#define NROWS 8192
#define NDIM  256
#define KNN   8
#define TCOL  32                          // j-cols per LDS tile (16 KiB)
#define BLK_ROWS 128                      // 4 waves x 32 rows (R=1)
#define JSPLIT 16
#define JRANGE (NROWS / JSPLIT)           // 512
#define NBX    (NROWS / BLK_ROWS)         // 64 row-blocks

typedef __attribute__((ext_vector_type(8)))  short bf16x8;
typedef __attribute__((ext_vector_type(16))) float f32x16;

// ---- workspace layout (bytes) ----
// ebT chunk-major: ushort ebT[32][NROWS][8] — chunk c holds dims 8c..8c+7.
#define WS_EBT 0                          // 4 MiB
#define WS_SQN (4*1024*1024)              // 32 KiB
#define WS_PCS (WS_SQN + 32*1024)         // 256 x 256 f32 = 256 KiB
#define WS_S2P (WS_PCS + 256*1024)        // 256 f32 = 1 KiB
#define WS_ACC (WS_S2P + 1024)            // gacc[0]=sum8 [1]=S2 [2]=Q [3]=cnt
#define WS_KNN (WS_ACC + 1024)            // [16][NROWS][KNN] f32 = 4 MiB

// e -> bf16 chunk-major (LDS-staged transpose -> coalesced 512B writes),
// per-row norms, per-block colsum/S2 partials. Block 0 zeroes gacc (only
// k_final — later in stream — reads it). No memset dispatch needed.
__global__ void k_prep(const float* __restrict__ e,
                       ushort* __restrict__ ebt,
                       float* __restrict__ sqn,
                       float* __restrict__ pcs,
                       float* __restrict__ s2p,
                       float* __restrict__ gacc) {
  __shared__ ushort tbuf[32 * 256];       // 16 KiB transpose tile
  __shared__ float  lcs[NDIM];            // colsum partial
  __shared__ float  s2red[4];
  char* const traw = reinterpret_cast<char*>(&tbuf[0]);

  const int tid  = threadIdx.x;
  const int lane = tid & 63;
  const int wv   = tid >> 6;
  const int rb   = blockIdx.x * 32;
  if (blockIdx.x == 0 && tid < 4) ((int*)gacc)[tid] = 0;
  lcs[tid] = 0.f;
  __syncthreads();

  const int g    = lane >> 1;             // 16B granule 0..31
  const int half = lane & 1;
  float4 cs = {0.f, 0.f, 0.f, 0.f};
  float s2loc = 0.f;
  #pragma unroll
  for (int r = 0; r < 8; ++r) {
    const int rl  = wv * 8 + r;           // row-local 0..31
    const int row = rb + rl;
    const float4 v = *reinterpret_cast<const float4*>(e + (size_t)row * NDIM + lane * 4);
    ushort4 o;
    __hip_bfloat16 b0 = __float2bfloat16(v.x), b1 = __float2bfloat16(v.y);
    __hip_bfloat16 b2 = __float2bfloat16(v.z), b3 = __float2bfloat16(v.w);
    o.x = *reinterpret_cast<ushort*>(&b0); o.y = *reinterpret_cast<ushort*>(&b1);
    o.z = *reinterpret_cast<ushort*>(&b2); o.w = *reinterpret_cast<ushort*>(&b3);
    // swizzled LDS store: granule g' = g ^ (rl&7)
    *reinterpret_cast<ushort4*>(
        traw + rl * 512 + ((g ^ (rl & 7)) * 16) + half * 8) = o;
    float acc = v.x*v.x + v.y*v.y + v.z*v.z + v.w*v.w;
    #pragma unroll
    for (int off = 32; off > 0; off >>= 1) acc += __shfl_down(acc, off);
    if (lane == 0) { sqn[row] = acc; s2loc += acc; }
    cs.x += v.x; cs.y += v.y; cs.z += v.z; cs.w += v.w;
  }
  atomicAdd(&lcs[lane * 4 + 0], cs.x);
  atomicAdd(&lcs[lane * 4 + 1], cs.y);
  atomicAdd(&lcs[lane * 4 + 2], cs.z);
  atomicAdd(&lcs[lane * 4 + 3], cs.w);
  if (lane == 0) s2red[wv] = s2loc;
  __syncthreads();

  // write-out: contiguous 512B per 32 lanes (chunk c, rows rb..rb+31)
  #pragma unroll
  for (int i = 0; i < 4; ++i) {
    const int c  = i * 8 + (tid >> 5);
    const int rl = tid & 31;
    const uint4 q = *reinterpret_cast<const uint4*>(
        traw + rl * 512 + ((c ^ (rl & 7)) * 16));
    *reinterpret_cast<uint4*>(ebt + (size_t)(c * NROWS + rb + rl) * 8) = q;
  }
  pcs[(size_t)blockIdx.x * NDIM + tid] = lcs[tid];
  if (tid == 0)
    s2p[blockIdx.x] = s2red[0] + s2red[1] + s2red[2] + s2red[3];
}

// ---- selection helpers (MAX-key; key = dot - nj/2, larger = nearer) ----
__device__ __forceinline__ void CEmax(float& x, float& y) {
  const float h = fmaxf(x, y);
  y = fminf(x, y);
  x = h;
}
__device__ __forceinline__ void clean8max(float* s) {   // bitonic -> descending
  CEmax(s[0],s[4]); CEmax(s[1],s[5]); CEmax(s[2],s[6]); CEmax(s[3],s[7]);
  CEmax(s[0],s[2]); CEmax(s[1],s[3]); CEmax(s[4],s[6]); CEmax(s[5],s[7]);
  CEmax(s[0],s[1]); CEmax(s[2],s[3]); CEmax(s[4],s[5]); CEmax(s[6],s[7]);
}
__device__ __forceinline__ void ins8max(float* m, const float c) {  // desc insert
  m[7] = __builtin_amdgcn_fmed3f(m[6], m[7], c);
  m[6] = __builtin_amdgcn_fmed3f(m[5], m[6], c);
  m[5] = __builtin_amdgcn_fmed3f(m[4], m[5], c);
  m[4] = __builtin_amdgcn_fmed3f(m[3], m[4], c);
  m[3] = __builtin_amdgcn_fmed3f(m[2], m[3], c);
  m[2] = __builtin_amdgcn_fmed3f(m[1], m[2], c);
  m[1] = __builtin_amdgcn_fmed3f(m[0], m[1], c);
  m[0] = fmaxf(m[0], c);
}
__device__ __forceinline__ void CEmin(float& x, float& y) {
  const float lo = fminf(x, y);
  y = fmaxf(x, y);
  x = lo;
}
__device__ __forceinline__ void clean8min(float* s) {   // bitonic -> ascending
  CEmin(s[0],s[4]); CEmin(s[1],s[5]); CEmin(s[2],s[6]); CEmin(s[3],s[7]);
  CEmin(s[0],s[2]); CEmin(s[1],s[3]); CEmin(s[4],s[6]); CEmin(s[5],s[7]);
  CEmin(s[0],s[1]); CEmin(s[2],s[3]); CEmin(s[4],s[5]); CEmin(s[6],s[7]);
}

// r13 k_main verbatim: R=1, 4 blocks/CU, chunk-major ebT, counted-vmcnt
// pipeline (loads never drained mid-loop), acc init = -nj/2.
__launch_bounds__(256, 4)
__global__ void k_main(const ushort* __restrict__ ebt,
                       const float* __restrict__ sqn,
                       float* __restrict__ knn_out) {
  __shared__ ushort lbuf[2][TCOL * NDIM];   // 2 x 16 KiB
  char* const lraw = reinterpret_cast<char*>(&lbuf[0][0]);

  const int tid  = threadIdx.x;
  const int lane = tid & 63;
  const int wv   = tid >> 6;
  const int col  = lane & 31;
  const int hi   = lane >> 5;
  const int rowi = blockIdx.x * BLK_ROWS + wv * 32 + col;
  const int split = blockIdx.y;
  const int jbase = split * JRANGE;

  bf16x8 ifr[16];
  #pragma unroll
  for (int kk = 0; kk < 16; ++kk)
    ifr[kk] = *reinterpret_cast<const bf16x8*>(
        ebt + (size_t)((2 * kk + hi) * NROWS + rowi) * 8);
  const float ni = sqn[rowi];

  float m[KNN];
  #pragma unroll
  for (int i = 0; i < KNN; ++i) m[i] = -1e30f;

  const ushort* sp[4];
  #pragma unroll
  for (int s = 0; s < 4; ++s) {
    const int c = s * 8 + (tid >> 5);
    sp[s] = ebt + (size_t)(c * NROWS + jbase + (tid & 31)) * 8;
  }
  const int lbase = hi * 512 + col * 16;

  auto STAGE = [&](int bufc) {
    #pragma unroll
    for (int s = 0; s < 4; ++s) {
      __builtin_amdgcn_global_load_lds(
          (const __attribute__((address_space(1))) void*)sp[s],
          (__attribute__((address_space(3))) void*)(
              lraw + bufc * 16384 + s * 4096 + wv * 1024),
          16, 0, 0);
      sp[s] += TCOL * 8;
    }
  };

  const float* njp = sqn + jbase;
  const int nT = JRANGE / TCOL;            // 16

  STAGE(0);
  STAGE(1);

  for (int t = 0; t < nT; ++t) {
    if (t + 1 < nT) {
      asm volatile("s_waitcnt vmcnt(4)" ::: "memory");
    } else {
      asm volatile("s_waitcnt vmcnt(0)" ::: "memory");
    }
    __builtin_amdgcn_s_barrier();
    asm volatile("" ::: "memory");

    {
      const int bufc = t & 1;
      f32x16 acc;
      #pragma unroll
      for (int g = 0; g < 4; ++g) {
        const float4 nj4 = *reinterpret_cast<const float4*>(njp + g * 8 + hi * 4);
        acc[g*4+0] = -0.5f * nj4.x; acc[g*4+1] = -0.5f * nj4.y;
        acc[g*4+2] = -0.5f * nj4.z; acc[g*4+3] = -0.5f * nj4.w;
      }
      #pragma unroll
      for (int kk = 0; kk < 16; ++kk) {
        const bf16x8 jf = *reinterpret_cast<const bf16x8*>(
            lraw + bufc * 16384 + kk * 1024 + lbase);
        acc = __builtin_amdgcn_mfma_f32_32x32x16_bf16(jf, ifr[kk], acc, 0, 0, 0);
      }
      #pragma unroll
      for (int q = 0; q < 16; ++q) ins8max(m, acc[q]);
      njp += TCOL;
    }

    asm volatile("" ::: "memory");
    __builtin_amdgcn_s_barrier();
    if (t + 2 < nT) STAGE(t & 1);
  }

  float g[KNN];
  #pragma unroll
  for (int k = 0; k < KNN; ++k)
    g[k] = fmaxf(m[k], __shfl_xor(m[KNN - 1 - k], 32));
  clean8max(g);
  if (hi == 0) {
    float* dst = knn_out + ((size_t)split * NROWS + rowi) * KNN;
    #pragma unroll
    for (int k = 0; k < KNN; ++k)
      dst[k] = fmaxf(fmaf(-2.0f, g[k], ni), 0.0f);   // ascending distances
  }
}

// 64 blocks x 128 rows; 2 threads/row (8 splits each) pair-merged via shfl.
// Block 0 also reduces colsum partials -> Q and s2 partials -> S2.
// Last finishing block (counter gacc[3]) computes the output scalar.
__global__ void k_final(const float* __restrict__ knn,
                        const float* __restrict__ pcs,
                        const float* __restrict__ s2p,
                        float* __restrict__ gacc,
                        float* __restrict__ out) {
  const int tid  = threadIdx.x;
  const int lane = tid & 63;
  const int wv   = tid >> 6;
  const int row  = blockIdx.x * 128 + (tid >> 1);
  const int sg   = (tid & 1) * 8;          // this thread's split range
  __shared__ float red[8];

  float m[KNN];
  {
    const float* p0 = knn + ((size_t)sg * NROWS + row) * KNN;
    #pragma unroll
    for (int i = 0; i < KNN; ++i) m[i] = p0[i];
  }
  #pragma unroll
  for (int s = 1; s < 8; ++s) {
    const float* p = knn + ((size_t)(sg + s) * NROWS + row) * KNN;
    float b[KNN];
    #pragma unroll
    for (int i = 0; i < KNN; ++i) b[i] = p[i];
    #pragma unroll
    for (int k = 0; k < KNN; ++k) m[k] = fminf(m[k], b[KNN - 1 - k]);
    clean8min(m);
  }
  // pair-merge (tid^1 holds the other 8 splits)
  float b[KNN];
  #pragma unroll
  for (int k = 0; k < KNN; ++k) b[k] = __shfl_xor(m[k], 1);
  #pragma unroll
  for (int k = 0; k < KNN; ++k) m[k] = fminf(m[k], b[KNN - 1 - k]);
  clean8min(m);

  float rs = 0.f;
  if ((tid & 1) == 0) {
    #pragma unroll
    for (int i = 0; i < KNN; ++i) rs += m[i];
  }
  #pragma unroll
  for (int off = 32; off > 0; off >>= 1) rs += __shfl_down(rs, off);
  if (lane == 0) red[wv] = rs;
  __syncthreads();
  if (tid == 0)
    atomicAdd(&gacc[0], red[0] + red[1] + red[2] + red[3]);

  if (blockIdx.x == 0) {
    // colsum partial reduce -> Q ; s2 partial reduce -> S2
    float cs = 0.f;
    for (int bb = 0; bb < 256; ++bb) cs += pcs[(size_t)bb * NDIM + tid];
    float q = cs * cs;
    float s2 = s2p[tid];
    #pragma unroll
    for (int off = 32; off > 0; off >>= 1) {
      q  += __shfl_down(q, off);
      s2 += __shfl_down(s2, off);
    }
    __syncthreads();
    if (lane == 0) { red[wv] = q; red[4 + wv] = s2; }
    __syncthreads();
    if (tid == 0) {
      atomicAdd(&gacc[2], red[0] + red[1] + red[2] + red[3]);
      atomicAdd(&gacc[1], red[4] + red[5] + red[6] + red[7]);
    }
  }
  // completion: last block computes the output scalar.
  if (tid == 0) {
    __threadfence();
    int* cnt = (int*)(gacc + 3);
    const int prev = atomicAdd(cnt, 1);
    if (prev == (int)gridDim.x - 1) {
      const float sum8 = atomicAdd(&gacc[0], 0.0f);
      const float S2   = atomicAdd(&gacc[1], 0.0f);
      const float Q    = atomicAdd(&gacc[2], 0.0f);
      const float ref_var = (S2 - Q / (float)NROWS) / ((float)NDIM * (float)(NROWS - 1));
      out[0] = (sum8 / (float)(NROWS * KNN)) / ref_var;
    }
  }
}

extern "C" void kernel_launch(void* const* d_in, const int* in_sizes, int n_in,
                              void* d_out, int out_size, void* d_ws, size_t ws_size,
                              hipStream_t stream) {
  const float* e = (const float*)d_in[0];
  char* ws = (char*)d_ws;
  ushort* ebt = (ushort*)(ws + WS_EBT);
  float* sqn  = (float*)(ws + WS_SQN);
  float* pcs  = (float*)(ws + WS_PCS);
  float* s2p  = (float*)(ws + WS_S2P);
  float* gacc = (float*)(ws + WS_ACC);
  float* knn  = (float*)(ws + WS_KNN);
  float* out  = (float*)d_out;

  hipLaunchKernelGGL(k_prep,  dim3(256), dim3(256), 0, stream,
                     e, ebt, sqn, pcs, s2p, gacc);
  hipLaunchKernelGGL(k_main,  dim3(NBX, JSPLIT), dim3(256), 0, stream,
                     ebt, sqn, knn);
  hipLaunchKernelGGL(k_final, dim3(64), dim3(256), 0, stream,
                     knn, pcs, s2p, gacc, out);
}

// Round 18
// 66.047 us; speedup vs baseline: 2.5132x; 1.0883x over previous
//
#include <hip/hip_runtime.h>
#include <hip/hip_bf16.h>

#define NROWS 8192
#define NDIM  256
#define KNN   8
#define TCOL  32                          // j-cols per LDS tile (16 KiB)
#define BLK_ROWS 128                      // 4 waves x 32 rows (R=1)
#define JSPLIT 16
#define JRANGE (NROWS / JSPLIT)           // 512
#define NBX    (NROWS / BLK_ROWS)         // 64 row-blocks

typedef __attribute__((ext_vector_type(8)))  short bf16x8;
typedef __attribute__((ext_vector_type(16))) float f32x16;

// ---- workspace layout (bytes) ----
// ebT chunk-major: ushort ebT[32][NROWS][8] — chunk c holds dims 8c..8c+7.
#define WS_EBT 0                          // 4 MiB
#define WS_SQN (4*1024*1024)              // 32 KiB
#define WS_PCS (WS_SQN + 32*1024)         // 256 x 256 f32 = 256 KiB
#define WS_S2P (WS_PCS + 256*1024)        // 256 f32 = 1 KiB
#define WS_ACC (WS_S2P + 1024)            // gacc[0]=sum8 [1]=S2 [2]=Q [3]=cnt
#define WS_KNN (WS_ACC + 1024)            // [16][NROWS][KNN] f32 = 4 MiB

// e -> bf16 chunk-major (LDS-staged transpose -> coalesced 512B writes),
// per-row norms, per-block colsum/S2 partials. Block 0 zeroes gacc.
__global__ void k_prep(const float* __restrict__ e,
                       ushort* __restrict__ ebt,
                       float* __restrict__ sqn,
                       float* __restrict__ pcs,
                       float* __restrict__ s2p,
                       float* __restrict__ gacc) {
  __shared__ ushort tbuf[32 * 256];       // 16 KiB transpose tile
  __shared__ float  lcs[NDIM];
  __shared__ float  s2red[4];
  char* const traw = reinterpret_cast<char*>(&tbuf[0]);

  const int tid  = threadIdx.x;
  const int lane = tid & 63;
  const int wv   = tid >> 6;
  const int rb   = blockIdx.x * 32;
  if (blockIdx.x == 0 && tid < 4) ((int*)gacc)[tid] = 0;
  lcs[tid] = 0.f;
  __syncthreads();

  const int g    = lane >> 1;             // 16B granule 0..31
  const int half = lane & 1;
  float4 cs = {0.f, 0.f, 0.f, 0.f};
  float s2loc = 0.f;
  #pragma unroll
  for (int r = 0; r < 8; ++r) {
    const int rl  = wv * 8 + r;
    const int row = rb + rl;
    const float4 v = *reinterpret_cast<const float4*>(e + (size_t)row * NDIM + lane * 4);
    ushort4 o;
    __hip_bfloat16 b0 = __float2bfloat16(v.x), b1 = __float2bfloat16(v.y);
    __hip_bfloat16 b2 = __float2bfloat16(v.z), b3 = __float2bfloat16(v.w);
    o.x = *reinterpret_cast<ushort*>(&b0); o.y = *reinterpret_cast<ushort*>(&b1);
    o.z = *reinterpret_cast<ushort*>(&b2); o.w = *reinterpret_cast<ushort*>(&b3);
    *reinterpret_cast<ushort4*>(
        traw + rl * 512 + ((g ^ (rl & 7)) * 16) + half * 8) = o;
    float acc = v.x*v.x + v.y*v.y + v.z*v.z + v.w*v.w;
    #pragma unroll
    for (int off = 32; off > 0; off >>= 1) acc += __shfl_down(acc, off);
    if (lane == 0) { sqn[row] = acc; s2loc += acc; }
    cs.x += v.x; cs.y += v.y; cs.z += v.z; cs.w += v.w;
  }
  atomicAdd(&lcs[lane * 4 + 0], cs.x);
  atomicAdd(&lcs[lane * 4 + 1], cs.y);
  atomicAdd(&lcs[lane * 4 + 2], cs.z);
  atomicAdd(&lcs[lane * 4 + 3], cs.w);
  if (lane == 0) s2red[wv] = s2loc;
  __syncthreads();

  #pragma unroll
  for (int i = 0; i < 4; ++i) {
    const int c  = i * 8 + (tid >> 5);
    const int rl = tid & 31;
    const uint4 q = *reinterpret_cast<const uint4*>(
        traw + rl * 512 + ((c ^ (rl & 7)) * 16));
    *reinterpret_cast<uint4*>(ebt + (size_t)(c * NROWS + rb + rl) * 8) = q;
  }
  pcs[(size_t)blockIdx.x * NDIM + tid] = lcs[tid];
  if (tid == 0)
    s2p[blockIdx.x] = s2red[0] + s2red[1] + s2red[2] + s2red[3];
}

// ---- selection helpers (MAX-key; key = dot - nj/2, larger = nearer) ----
__device__ __forceinline__ void CEmax(float& x, float& y) {
  const float h = fmaxf(x, y);
  y = fminf(x, y);
  x = h;
}
__device__ __forceinline__ void clean8max(float* s) {   // bitonic -> descending
  CEmax(s[0],s[4]); CEmax(s[1],s[5]); CEmax(s[2],s[6]); CEmax(s[3],s[7]);
  CEmax(s[0],s[2]); CEmax(s[1],s[3]); CEmax(s[4],s[6]); CEmax(s[5],s[7]);
  CEmax(s[0],s[1]); CEmax(s[2],s[3]); CEmax(s[4],s[5]); CEmax(s[6],s[7]);
}
__device__ __forceinline__ void ins8max(float* m, const float c) {  // desc insert
  m[7] = __builtin_amdgcn_fmed3f(m[6], m[7], c);
  m[6] = __builtin_amdgcn_fmed3f(m[5], m[6], c);
  m[5] = __builtin_amdgcn_fmed3f(m[4], m[5], c);
  m[4] = __builtin_amdgcn_fmed3f(m[3], m[4], c);
  m[3] = __builtin_amdgcn_fmed3f(m[2], m[3], c);
  m[2] = __builtin_amdgcn_fmed3f(m[1], m[2], c);
  m[1] = __builtin_amdgcn_fmed3f(m[0], m[1], c);
  m[0] = fmaxf(m[0], c);
}
__device__ __forceinline__ void CEmin(float& x, float& y) {
  const float lo = fminf(x, y);
  y = fmaxf(x, y);
  x = lo;
}
__device__ __forceinline__ void clean8min(float* s) {   // bitonic -> ascending
  CEmin(s[0],s[4]); CEmin(s[1],s[5]); CEmin(s[2],s[6]); CEmin(s[3],s[7]);
  CEmin(s[0],s[2]); CEmin(s[1],s[3]); CEmin(s[4],s[6]); CEmin(s[5],s[7]);
  CEmin(s[0],s[1]); CEmin(s[2],s[3]); CEmin(s[4],s[5]); CEmin(s[6],s[7]);
}

// r13 core + nj moved to LDS (lsqn): the per-iter nj global loads were
// FIFO-ordered AFTER the stage loads in vmcnt, so consuming them forced
// vmcnt(0) every iteration — silently draining the counted-vmcnt pipeline.
// With nj on lgkmcnt instead, vmcnt(4) really does keep one tile in flight.
__launch_bounds__(256, 4)
__global__ void k_main(const ushort* __restrict__ ebt,
                       const float* __restrict__ sqn,
                       float* __restrict__ knn_out) {
  __shared__ ushort lbuf[2][TCOL * NDIM];   // 2 x 16 KiB
  __shared__ float  lsqn[JRANGE];           // 2 KiB
  char* const lraw = reinterpret_cast<char*>(&lbuf[0][0]);

  const int tid  = threadIdx.x;
  const int lane = tid & 63;
  const int wv   = tid >> 6;
  const int col  = lane & 31;
  const int hi   = lane >> 5;
  const int rowi = blockIdx.x * BLK_ROWS + wv * 32 + col;
  const int split = blockIdx.y;
  const int jbase = split * JRANGE;

  bf16x8 ifr[16];
  #pragma unroll
  for (int kk = 0; kk < 16; ++kk)
    ifr[kk] = *reinterpret_cast<const bf16x8*>(
        ebt + (size_t)((2 * kk + hi) * NROWS + rowi) * 8);
  const float ni = sqn[rowi];

  float m[KNN];
  #pragma unroll
  for (int i = 0; i < KNN; ++i) m[i] = -1e30f;

  const ushort* sp[4];
  #pragma unroll
  for (int s = 0; s < 4; ++s) {
    const int c = s * 8 + (tid >> 5);
    sp[s] = ebt + (size_t)(c * NROWS + jbase + (tid & 31)) * 8;
  }
  const int lbase = hi * 512 + col * 16;

  auto STAGE = [&](int bufc) {
    #pragma unroll
    for (int s = 0; s < 4; ++s) {
      __builtin_amdgcn_global_load_lds(
          (const __attribute__((address_space(1))) void*)sp[s],
          (__attribute__((address_space(3))) void*)(
              lraw + bufc * 16384 + s * 4096 + wv * 1024),
          16, 0, 0);
      sp[s] += TCOL * 8;
    }
  };

  const int nT = JRANGE / TCOL;            // 16

  STAGE(0);
  STAGE(1);
  // nj slice -> LDS (keeps nj off vmcnt inside the loop)
  #pragma unroll
  for (int i = 0; i < JRANGE / 256; ++i) lsqn[tid + i * 256] = sqn[jbase + tid + i * 256];
  __syncthreads();   // one-time full drain: tiles 0,1 + lsqn all visible

  for (int t = 0; t < nT; ++t) {
    if (t + 1 < nT) {
      asm volatile("s_waitcnt vmcnt(4)" ::: "memory");  // tile t landed
    } else {
      asm volatile("s_waitcnt vmcnt(0)" ::: "memory");
    }
    __builtin_amdgcn_s_barrier();
    asm volatile("" ::: "memory");

    {
      const int bufc = t & 1;
      f32x16 acc;
      #pragma unroll
      for (int g = 0; g < 4; ++g) {
        const float4 nj4 = *reinterpret_cast<const float4*>(
            &lsqn[t * TCOL + g * 8 + hi * 4]);        // ds_read (lgkmcnt)
        acc[g*4+0] = -0.5f * nj4.x; acc[g*4+1] = -0.5f * nj4.y;
        acc[g*4+2] = -0.5f * nj4.z; acc[g*4+3] = -0.5f * nj4.w;
      }
      __builtin_amdgcn_s_setprio(1);
      #pragma unroll
      for (int kk = 0; kk < 16; ++kk) {
        const bf16x8 jf = *reinterpret_cast<const bf16x8*>(
            lraw + bufc * 16384 + kk * 1024 + lbase);
        acc = __builtin_amdgcn_mfma_f32_32x32x16_bf16(jf, ifr[kk], acc, 0, 0, 0);
      }
      __builtin_amdgcn_s_setprio(0);
      #pragma unroll
      for (int q = 0; q < 16; ++q) ins8max(m, acc[q]);
    }

    asm volatile("" ::: "memory");
    __builtin_amdgcn_s_barrier();
    if (t + 2 < nT) STAGE(t & 1);          // only stage loads on vmcnt
  }

  float g[KNN];
  #pragma unroll
  for (int k = 0; k < KNN; ++k)
    g[k] = fmaxf(m[k], __shfl_xor(m[KNN - 1 - k], 32));
  clean8max(g);
  if (hi == 0) {
    float* dst = knn_out + ((size_t)split * NROWS + rowi) * KNN;
    #pragma unroll
    for (int k = 0; k < KNN; ++k)
      dst[k] = fmaxf(fmaf(-2.0f, g[k], ni), 0.0f);   // ascending distances
  }
}

// 64 blocks x 128 rows; 2 threads/row (8 splits each) pair-merged via shfl.
// Q reduction distributed over blocks 0..3 (64 dims each); S2 in block 0.
// Last finishing block (counter gacc[3]) computes the output scalar.
__global__ void k_final(const float* __restrict__ knn,
                        const float* __restrict__ pcs,
                        const float* __restrict__ s2p,
                        float* __restrict__ gacc,
                        float* __restrict__ out) {
  const int tid  = threadIdx.x;
  const int lane = tid & 63;
  const int wv   = tid >> 6;
  const int row  = blockIdx.x * 128 + (tid >> 1);
  const int sg   = (tid & 1) * 8;
  __shared__ float red[12];

  float m[KNN];
  {
    const float* p0 = knn + ((size_t)sg * NROWS + row) * KNN;
    #pragma unroll
    for (int i = 0; i < KNN; ++i) m[i] = p0[i];
  }
  #pragma unroll
  for (int s = 1; s < 8; ++s) {
    const float* p = knn + ((size_t)(sg + s) * NROWS + row) * KNN;
    float b[KNN];
    #pragma unroll
    for (int i = 0; i < KNN; ++i) b[i] = p[i];
    #pragma unroll
    for (int k = 0; k < KNN; ++k) m[k] = fminf(m[k], b[KNN - 1 - k]);
    clean8min(m);
  }
  float b[KNN];
  #pragma unroll
  for (int k = 0; k < KNN; ++k) b[k] = __shfl_xor(m[k], 1);
  #pragma unroll
  for (int k = 0; k < KNN; ++k) m[k] = fminf(m[k], b[KNN - 1 - k]);
  clean8min(m);

  float rs = 0.f;
  if ((tid & 1) == 0) {
    #pragma unroll
    for (int i = 0; i < KNN; ++i) rs += m[i];
  }
  #pragma unroll
  for (int off = 32; off > 0; off >>= 1) rs += __shfl_down(rs, off);
  if (lane == 0) red[wv] = rs;
  __syncthreads();
  if (tid == 0)
    atomicAdd(&gacc[0], red[0] + red[1] + red[2] + red[3]);

  if (blockIdx.x < 4) {
    // Q: this block handles 64 dims; 4 threads per dim over 256 partials.
    const int dim = blockIdx.x * 64 + (tid >> 2);
    const int sl  = tid & 3;
    float s = 0.f;
    #pragma unroll 8
    for (int k = 0; k < 64; ++k)
      s += pcs[(size_t)(sl * 64 + k) * NDIM + dim];
    s += __shfl_xor(s, 1);
    s += __shfl_xor(s, 2);                 // full colsum for dim
    float q = (sl == 0) ? s * s : 0.f;
    #pragma unroll
    for (int off = 32; off > 0; off >>= 1) q += __shfl_down(q, off);
    if (lane == 0) red[4 + wv] = q;
    __syncthreads();
    if (tid == 0)
      atomicAdd(&gacc[2], red[4] + red[5] + red[6] + red[7]);
  }
  if (blockIdx.x == 0) {
    float s2 = s2p[tid];
    #pragma unroll
    for (int off = 32; off > 0; off >>= 1) s2 += __shfl_down(s2, off);
    if (lane == 0) red[8 + wv] = s2;
    __syncthreads();
    if (tid == 0)
      atomicAdd(&gacc[1], red[8] + red[9] + red[10] + red[11]);
  }
  // completion: last block computes the output scalar.
  if (tid == 0) {
    __threadfence();
    int* cnt = (int*)(gacc + 3);
    const int prev = atomicAdd(cnt, 1);
    if (prev == (int)gridDim.x - 1) {
      const float sum8 = atomicAdd(&gacc[0], 0.0f);
      const float S2   = atomicAdd(&gacc[1], 0.0f);
      const float Q    = atomicAdd(&gacc[2], 0.0f);
      const float ref_var = (S2 - Q / (float)NROWS) / ((float)NDIM * (float)(NROWS - 1));
      out[0] = (sum8 / (float)(NROWS * KNN)) / ref_var;
    }
  }
}

extern "C" void kernel_launch(void* const* d_in, const int* in_sizes, int n_in,
                              void* d_out, int out_size, void* d_ws, size_t ws_size,
                              hipStream_t stream) {
  const float* e = (const float*)d_in[0];
  char* ws = (char*)d_ws;
  ushort* ebt = (ushort*)(ws + WS_EBT);
  float* sqn  = (float*)(ws + WS_SQN);
  float* pcs  = (float*)(ws + WS_PCS);
  float* s2p  = (float*)(ws + WS_S2P);
  float* gacc = (float*)(ws + WS_ACC);
  float* knn  = (float*)(ws + WS_KNN);
  float* out  = (float*)d_out;

  hipLaunchKernelGGL(k_prep,  dim3(256), dim3(256), 0, stream,
                     e, ebt, sqn, pcs, s2p, gacc);
  hipLaunchKernelGGL(k_main,  dim3(NBX, JSPLIT), dim3(256), 0, stream,
                     ebt, sqn, knn);
  hipLaunchKernelGGL(k_final, dim3(64), dim3(256), 0, stream,
                     knn, pcs, s2p, gacc, out);
}

// Round 19
// 65.269 us; speedup vs baseline: 2.5432x; 1.0119x over previous
//
#include <hip/hip_runtime.h>
#include <hip/hip_bf16.h>

#define NROWS 8192
#define NDIM  256
#define KNN   8
#define TCOL  32                          // j-cols per LDS tile (16 KiB)
#define BLK_ROWS 128                      // 4 waves x 32 rows (R=1)
#define JSPLIT 16
#define JRANGE (NROWS / JSPLIT)           // 512
#define NBX    (NROWS / BLK_ROWS)         // 64 row-blocks

typedef __attribute__((ext_vector_type(8)))  short bf16x8;
typedef __attribute__((ext_vector_type(16))) float f32x16;

// ---- workspace layout (bytes) ----
// ebT chunk-major: ushort ebT[32][NROWS][8] — chunk c holds dims 8c..8c+7.
#define WS_EBT 0                          // 4 MiB
#define WS_SQN (4*1024*1024)              // 32 KiB
#define WS_PCS (WS_SQN + 32*1024)         // 256 x 256 f32 = 256 KiB
#define WS_S2P (WS_PCS + 256*1024)        // 256 f32 = 1 KiB
#define WS_ACC (WS_S2P + 1024)            // gacc[0]=sum8 [1]=S2 [2]=Q [3]=cnt
#define WS_KNN (WS_ACC + 1024)            // [16][NROWS][KNN] f32 = 4 MiB

// e -> bf16 chunk-major (LDS-staged transpose -> coalesced 512B writes),
// per-row norms, per-block colsum/S2 partials. Block 0 zeroes gacc.
__global__ void k_prep(const float* __restrict__ e,
                       ushort* __restrict__ ebt,
                       float* __restrict__ sqn,
                       float* __restrict__ pcs,
                       float* __restrict__ s2p,
                       float* __restrict__ gacc) {
  __shared__ ushort tbuf[32 * 256];       // 16 KiB transpose tile
  __shared__ float  lcs[NDIM];
  __shared__ float  s2red[4];
  char* const traw = reinterpret_cast<char*>(&tbuf[0]);

  const int tid  = threadIdx.x;
  const int lane = tid & 63;
  const int wv   = tid >> 6;
  const int rb   = blockIdx.x * 32;
  if (blockIdx.x == 0 && tid < 4) ((int*)gacc)[tid] = 0;
  lcs[tid] = 0.f;
  __syncthreads();

  const int g    = lane >> 1;             // 16B granule 0..31
  const int half = lane & 1;
  float4 cs = {0.f, 0.f, 0.f, 0.f};
  float s2loc = 0.f;
  #pragma unroll
  for (int r = 0; r < 8; ++r) {
    const int rl  = wv * 8 + r;
    const int row = rb + rl;
    const float4 v = *reinterpret_cast<const float4*>(e + (size_t)row * NDIM + lane * 4);
    ushort4 o;
    __hip_bfloat16 b0 = __float2bfloat16(v.x), b1 = __float2bfloat16(v.y);
    __hip_bfloat16 b2 = __float2bfloat16(v.z), b3 = __float2bfloat16(v.w);
    o.x = *reinterpret_cast<ushort*>(&b0); o.y = *reinterpret_cast<ushort*>(&b1);
    o.z = *reinterpret_cast<ushort*>(&b2); o.w = *reinterpret_cast<ushort*>(&b3);
    *reinterpret_cast<ushort4*>(
        traw + rl * 512 + ((g ^ (rl & 7)) * 16) + half * 8) = o;
    float acc = v.x*v.x + v.y*v.y + v.z*v.z + v.w*v.w;
    #pragma unroll
    for (int off = 32; off > 0; off >>= 1) acc += __shfl_down(acc, off);
    if (lane == 0) { sqn[row] = acc; s2loc += acc; }
    cs.x += v.x; cs.y += v.y; cs.z += v.z; cs.w += v.w;
  }
  atomicAdd(&lcs[lane * 4 + 0], cs.x);
  atomicAdd(&lcs[lane * 4 + 1], cs.y);
  atomicAdd(&lcs[lane * 4 + 2], cs.z);
  atomicAdd(&lcs[lane * 4 + 3], cs.w);
  if (lane == 0) s2red[wv] = s2loc;
  __syncthreads();

  #pragma unroll
  for (int i = 0; i < 4; ++i) {
    const int c  = i * 8 + (tid >> 5);
    const int rl = tid & 31;
    const uint4 q = *reinterpret_cast<const uint4*>(
        traw + rl * 512 + ((c ^ (rl & 7)) * 16));
    *reinterpret_cast<uint4*>(ebt + (size_t)(c * NROWS + rb + rl) * 8) = q;
  }
  pcs[(size_t)blockIdx.x * NDIM + tid] = lcs[tid];
  if (tid == 0)
    s2p[blockIdx.x] = s2red[0] + s2red[1] + s2red[2] + s2red[3];
}

// ---- selection helpers (MAX-key; key = dot - nj/2, larger = nearer) ----
__device__ __forceinline__ void CEmax(float& x, float& y) {
  const float h = fmaxf(x, y);
  y = fminf(x, y);
  x = h;
}
__device__ __forceinline__ void clean8max(float* s) {   // bitonic -> descending
  CEmax(s[0],s[4]); CEmax(s[1],s[5]); CEmax(s[2],s[6]); CEmax(s[3],s[7]);
  CEmax(s[0],s[2]); CEmax(s[1],s[3]); CEmax(s[4],s[6]); CEmax(s[5],s[7]);
  CEmax(s[0],s[1]); CEmax(s[2],s[3]); CEmax(s[4],s[5]); CEmax(s[6],s[7]);
}
__device__ __forceinline__ void ins8max(float* m, const float c) {  // desc insert
  m[7] = __builtin_amdgcn_fmed3f(m[6], m[7], c);
  m[6] = __builtin_amdgcn_fmed3f(m[5], m[6], c);
  m[5] = __builtin_amdgcn_fmed3f(m[4], m[5], c);
  m[4] = __builtin_amdgcn_fmed3f(m[3], m[4], c);
  m[3] = __builtin_amdgcn_fmed3f(m[2], m[3], c);
  m[2] = __builtin_amdgcn_fmed3f(m[1], m[2], c);
  m[1] = __builtin_amdgcn_fmed3f(m[0], m[1], c);
  m[0] = fmaxf(m[0], c);
}
__device__ __forceinline__ void CEmin(float& x, float& y) {
  const float lo = fminf(x, y);
  y = fmaxf(x, y);
  x = lo;
}
__device__ __forceinline__ void clean8min(float* s) {   // bitonic -> ascending
  CEmin(s[0],s[4]); CEmin(s[1],s[5]); CEmin(s[2],s[6]); CEmin(s[3],s[7]);
  CEmin(s[0],s[2]); CEmin(s[1],s[3]); CEmin(s[4],s[6]); CEmin(s[5],s[7]);
  CEmin(s[0],s[1]); CEmin(s[2],s[3]); CEmin(s[4],s[5]); CEmin(s[6],s[7]);
}

// r18 core + (a) lsqn stores -nj/2 (acc-init is a pure LDS copy, no v_mul),
// (b) selection split into two independent chains mX (acc[0..7]) and
// mY (acc[8..15]) — serial med3 depth per iteration halves; merged once
// at the epilogue. Live regs ~115 < 128 (no spill at 4 blocks/CU).
__launch_bounds__(256, 4)
__global__ void k_main(const ushort* __restrict__ ebt,
                       const float* __restrict__ sqn,
                       float* __restrict__ knn_out) {
  __shared__ ushort lbuf[2][TCOL * NDIM];   // 2 x 16 KiB
  __shared__ float  lsqn[JRANGE];           // 2 KiB, holds -nj/2
  char* const lraw = reinterpret_cast<char*>(&lbuf[0][0]);

  const int tid  = threadIdx.x;
  const int lane = tid & 63;
  const int wv   = tid >> 6;
  const int col  = lane & 31;
  const int hi   = lane >> 5;
  const int rowi = blockIdx.x * BLK_ROWS + wv * 32 + col;
  const int split = blockIdx.y;
  const int jbase = split * JRANGE;

  bf16x8 ifr[16];
  #pragma unroll
  for (int kk = 0; kk < 16; ++kk)
    ifr[kk] = *reinterpret_cast<const bf16x8*>(
        ebt + (size_t)((2 * kk + hi) * NROWS + rowi) * 8);
  const float ni = sqn[rowi];

  float mX[KNN], mY[KNN];
  #pragma unroll
  for (int i = 0; i < KNN; ++i) { mX[i] = -1e30f; mY[i] = -1e30f; }

  const ushort* sp[4];
  #pragma unroll
  for (int s = 0; s < 4; ++s) {
    const int c = s * 8 + (tid >> 5);
    sp[s] = ebt + (size_t)(c * NROWS + jbase + (tid & 31)) * 8;
  }
  const int lbase = hi * 512 + col * 16;

  auto STAGE = [&](int bufc) {
    #pragma unroll
    for (int s = 0; s < 4; ++s) {
      __builtin_amdgcn_global_load_lds(
          (const __attribute__((address_space(1))) void*)sp[s],
          (__attribute__((address_space(3))) void*)(
              lraw + bufc * 16384 + s * 4096 + wv * 1024),
          16, 0, 0);
      sp[s] += TCOL * 8;
    }
  };

  const int nT = JRANGE / TCOL;            // 16

  STAGE(0);
  STAGE(1);
  // pre-negated norms -> LDS (keeps nj off vmcnt; deletes per-iter v_mul)
  #pragma unroll
  for (int i = 0; i < JRANGE / 256; ++i)
    lsqn[tid + i * 256] = -0.5f * sqn[jbase + tid + i * 256];
  __syncthreads();   // one-time full drain: tiles 0,1 + lsqn all visible

  for (int t = 0; t < nT; ++t) {
    if (t + 1 < nT) {
      asm volatile("s_waitcnt vmcnt(4)" ::: "memory");  // tile t landed
    } else {
      asm volatile("s_waitcnt vmcnt(0)" ::: "memory");
    }
    __builtin_amdgcn_s_barrier();
    asm volatile("" ::: "memory");

    {
      const int bufc = t & 1;
      f32x16 acc;
      #pragma unroll
      for (int g = 0; g < 4; ++g) {
        const float4 nj4 = *reinterpret_cast<const float4*>(
            &lsqn[t * TCOL + g * 8 + hi * 4]);        // ds_read of -nj/2
        acc[g*4+0] = nj4.x; acc[g*4+1] = nj4.y;
        acc[g*4+2] = nj4.z; acc[g*4+3] = nj4.w;
      }
      __builtin_amdgcn_s_setprio(1);
      #pragma unroll
      for (int kk = 0; kk < 16; ++kk) {
        const bf16x8 jf = *reinterpret_cast<const bf16x8*>(
            lraw + bufc * 16384 + kk * 1024 + lbase);
        acc = __builtin_amdgcn_mfma_f32_32x32x16_bf16(jf, ifr[kk], acc, 0, 0, 0);
      }
      __builtin_amdgcn_s_setprio(0);
      // two independent selection chains (halved serial med3 depth)
      #pragma unroll
      for (int q = 0; q < 8; ++q) {
        ins8max(mX, acc[q]);
        ins8max(mY, acc[q + 8]);
      }
    }

    asm volatile("" ::: "memory");
    __builtin_amdgcn_s_barrier();
    if (t + 2 < nT) STAGE(t & 1);          // only stage loads on vmcnt
  }

  // merge the two per-lane desc lists: top-8(X∪Y) = max(mX_k, mY_{7-k})
  float m[KNN];
  #pragma unroll
  for (int k = 0; k < KNN; ++k) m[k] = fmaxf(mX[k], mY[KNN - 1 - k]);
  clean8max(m);

  float g[KNN];
  #pragma unroll
  for (int k = 0; k < KNN; ++k)
    g[k] = fmaxf(m[k], __shfl_xor(m[KNN - 1 - k], 32));
  clean8max(g);
  if (hi == 0) {
    float* dst = knn_out + ((size_t)split * NROWS + rowi) * KNN;
    #pragma unroll
    for (int k = 0; k < KNN; ++k)
      dst[k] = fmaxf(fmaf(-2.0f, g[k], ni), 0.0f);   // ascending distances
  }
}

// 64 blocks x 128 rows; 2 threads/row (8 splits each) pair-merged via shfl.
// Q reduction distributed over blocks 0..3; S2 in block 0.
// Last finishing block (counter gacc[3]) computes the output scalar.
__global__ void k_final(const float* __restrict__ knn,
                        const float* __restrict__ pcs,
                        const float* __restrict__ s2p,
                        float* __restrict__ gacc,
                        float* __restrict__ out) {
  const int tid  = threadIdx.x;
  const int lane = tid & 63;
  const int wv   = tid >> 6;
  const int row  = blockIdx.x * 128 + (tid >> 1);
  const int sg   = (tid & 1) * 8;
  __shared__ float red[12];

  float m[KNN];
  {
    const float* p0 = knn + ((size_t)sg * NROWS + row) * KNN;
    #pragma unroll
    for (int i = 0; i < KNN; ++i) m[i] = p0[i];
  }
  #pragma unroll
  for (int s = 1; s < 8; ++s) {
    const float* p = knn + ((size_t)(sg + s) * NROWS + row) * KNN;
    float b[KNN];
    #pragma unroll
    for (int i = 0; i < KNN; ++i) b[i] = p[i];
    #pragma unroll
    for (int k = 0; k < KNN; ++k) m[k] = fminf(m[k], b[KNN - 1 - k]);
    clean8min(m);
  }
  float b[KNN];
  #pragma unroll
  for (int k = 0; k < KNN; ++k) b[k] = __shfl_xor(m[k], 1);
  #pragma unroll
  for (int k = 0; k < KNN; ++k) m[k] = fminf(m[k], b[KNN - 1 - k]);
  clean8min(m);

  float rs = 0.f;
  if ((tid & 1) == 0) {
    #pragma unroll
    for (int i = 0; i < KNN; ++i) rs += m[i];
  }
  #pragma unroll
  for (int off = 32; off > 0; off >>= 1) rs += __shfl_down(rs, off);
  if (lane == 0) red[wv] = rs;
  __syncthreads();
  if (tid == 0)
    atomicAdd(&gacc[0], red[0] + red[1] + red[2] + red[3]);

  if (blockIdx.x < 4) {
    const int dim = blockIdx.x * 64 + (tid >> 2);
    const int sl  = tid & 3;
    float s = 0.f;
    #pragma unroll 8
    for (int k = 0; k < 64; ++k)
      s += pcs[(size_t)(sl * 64 + k) * NDIM + dim];
    s += __shfl_xor(s, 1);
    s += __shfl_xor(s, 2);
    float q = (sl == 0) ? s * s : 0.f;
    #pragma unroll
    for (int off = 32; off > 0; off >>= 1) q += __shfl_down(q, off);
    if (lane == 0) red[4 + wv] = q;
    __syncthreads();
    if (tid == 0)
      atomicAdd(&gacc[2], red[4] + red[5] + red[6] + red[7]);
  }
  if (blockIdx.x == 0) {
    float s2 = s2p[tid];
    #pragma unroll
    for (int off = 32; off > 0; off >>= 1) s2 += __shfl_down(s2, off);
    if (lane == 0) red[8 + wv] = s2;
    __syncthreads();
    if (tid == 0)
      atomicAdd(&gacc[1], red[8] + red[9] + red[10] + red[11]);
  }
  // completion: last block computes the output scalar.
  if (tid == 0) {
    __threadfence();
    int* cnt = (int*)(gacc + 3);
    const int prev = atomicAdd(cnt, 1);
    if (prev == (int)gridDim.x - 1) {
      const float sum8 = atomicAdd(&gacc[0], 0.0f);
      const float S2   = atomicAdd(&gacc[1], 0.0f);
      const float Q    = atomicAdd(&gacc[2], 0.0f);
      const float ref_var = (S2 - Q / (float)NROWS) / ((float)NDIM * (float)(NROWS - 1));
      out[0] = (sum8 / (float)(NROWS * KNN)) / ref_var;
    }
  }
}

extern "C" void kernel_launch(void* const* d_in, const int* in_sizes, int n_in,
                              void* d_out, int out_size, void* d_ws, size_t ws_size,
                              hipStream_t stream) {
  const float* e = (const float*)d_in[0];
  char* ws = (char*)d_ws;
  ushort* ebt = (ushort*)(ws + WS_EBT);
  float* sqn  = (float*)(ws + WS_SQN);
  float* pcs  = (float*)(ws + WS_PCS);
  float* s2p  = (float*)(ws + WS_S2P);
  float* gacc = (float*)(ws + WS_ACC);
  float* knn  = (float*)(ws + WS_KNN);
  float* out  = (float*)d_out;

  hipLaunchKernelGGL(k_prep,  dim3(256), dim3(256), 0, stream,
                     e, ebt, sqn, pcs, s2p, gacc);
  hipLaunchKernelGGL(k_main,  dim3(NBX, JSPLIT), dim3(256), 0, stream,
                     ebt, sqn, knn);
  hipLaunchKernelGGL(k_final, dim3(64), dim3(256), 0, stream,
                     knn, pcs, s2p, gacc, out);
}